// Round 9
// baseline (202.971 us; speedup 1.0000x reference)
//
#include <hip/hip_runtime.h>
#include <hip/hip_bf16.h>

#define BI   4
#define LI   256
#define EI   768
#define DI   1536
#define NI   16
#define RI   48
#define KI   4
#define NDIRS 4
#define F2D  3072              // 2*D
#define MROWS 1024             // B*L
#define LOG2E 1.4426950408889634f
#define LN2   0.6931471805599453f

typedef float    floatx2 __attribute__((ext_vector_type(2)));
typedef float    floatx4 __attribute__((ext_vector_type(4)));
typedef _Float16 halfx2  __attribute__((ext_vector_type(2)));
typedef _Float16 halfx4  __attribute__((ext_vector_type(4)));
typedef _Float16 halfx8  __attribute__((ext_vector_type(8)));

typedef __attribute__((address_space(3))) unsigned lds_u32;
typedef __attribute__((address_space(1))) const unsigned glb_u32;

__device__ __forceinline__ void load16(const _Float16* g, _Float16* l) {
    __builtin_amdgcn_global_load_lds((glb_u32*)g, (lds_u32*)l, 16, 0, 0);
}

__device__ __forceinline__ int perm_idx(int dir, int j) {
    switch (dir) {
        case 0:  return j;
        case 1:  return 255 - j;
        case 2:  return ((j & 15) << 4) | (j >> 4);
        default: return 255 - (((j & 15) << 4) | (j >> 4));
    }
}

// DPP-based add of a permuted copy (VALU pipe, no LDS traffic).
template<int CTRL>
__device__ __forceinline__ float dpp_add(float p) {
    int t = __builtin_amdgcn_update_dpp(0, __builtin_bit_cast(int, p),
                                        CTRL, 0xf, 0xf, true);
    return p + __builtin_bit_cast(float, t);
}
// sum over 8 consecutive lanes (tid&7 group)
__device__ __forceinline__ float grp8_sum(float p) {
    p = dpp_add<0xB1>(p);    // quad_perm [1,0,3,2]  : xor 1
    p = dpp_add<0x4E>(p);    // quad_perm [2,3,0,1]  : xor 2
    p = dpp_add<0x141>(p);   // row_half_mirror      : combine quads
    return p;
}

// ---------------------------------------------------------------------------
// Tiled hi/lo-fp16 GEMM core, COUNTED-VMCNT 2-phase pipeline: per chunk
// {issue stage(c+1) -> s_waitcnt vmcnt(VM) [own c-loads done] -> s_barrier ->
// ds_read+MFMA -> lgkmcnt(0) -> s_barrier}. Loads for c+1 stay in flight
// across the whole compute of c. Race audit: bottom lgkmcnt(0)+barrier of
// iter c-1 ensures all waves done reading buf^1 before stage(c+1) writes it;
// top barrier ensures every wave's own c-loads landed before ds_reads.
// VM = per-wave loads issued per stage (min across waves when non-uniform).
// smem = 2x(BM+BN)*64 halfs.
// ---------------------------------------------------------------------------
template<int BM, int BN, int WGN, int FM, int FN, int VM>
__device__ __forceinline__ void gemm_core(const _Float16* __restrict__ Ah,
                                          const _Float16* __restrict__ Al, int lda,
                                          const _Float16* __restrict__ Bh,
                                          const _Float16* __restrict__ Bl, int ldb,
                                          int nChunks, _Float16* smem,
                                          floatx4 (&acc)[FM][FN]) {
    const int tid = threadIdx.x, lane = tid & 63, wave = tid >> 6;
    const int wave_m = wave / WGN, wave_n = wave % WGN;
    const int rr = lane & 15, koff = (lane >> 4) * 8;
    const int arow = wave_m * FM * 16, brow = wave_n * FN * 16;
    constexpr int BUFSZ = (BM + BN) * 64;

    auto stage = [&](int c, int bf) {
        _Float16* sAh = smem + bf * BUFSZ;
        _Float16* sAl = sAh + BM * 32;
        _Float16* sBh = sAh + BM * 64;
        _Float16* sBl = sAh + BM * 64 + BN * 32;
        for (int idx = tid; idx < BM * 4; idx += 256) {
            int r = idx >> 2, s = (idx & 3) * 8;
            load16(Ah + (size_t)r * lda + c * 32 + s, sAh + idx * 8);
            load16(Al + (size_t)r * lda + c * 32 + s, sAl + idx * 8);
        }
        for (int idx = tid; idx < BN * 4; idx += 256) {
            int r = idx >> 2, s = (idx & 3) * 8;
            load16(Bh + (size_t)r * ldb + c * 32 + s, sBh + idx * 8);
            load16(Bl + (size_t)r * ldb + c * 32 + s, sBl + idx * 8);
        }
    };

    stage(0, 0);

    for (int c = 0; c < nChunks; ++c) {
        const int bf = c & 1;
        if (c + 1 < nChunks) {
            stage(c + 1, bf ^ 1);              // issue-early into the other buffer
            asm volatile("s_waitcnt vmcnt(%0)" :: "n"(VM) : "memory");  // own c-loads done
        } else {
            asm volatile("s_waitcnt vmcnt(0)" ::: "memory");
        }
        __builtin_amdgcn_s_barrier();          // all waves' c-loads landed

        const _Float16* sAh = smem + bf * BUFSZ;
        const _Float16* sAl = sAh + BM * 32;
        const _Float16* sBh = sAh + BM * 64;
        const _Float16* sBl = sAh + BM * 64 + BN * 32;
        halfx8 ahf[FM], alf[FM], bhf[FN], blf[FN];
        #pragma unroll
        for (int i = 0; i < FM; ++i) {
            ahf[i] = *(const halfx8*)(sAh + (arow + i * 16 + rr) * 32 + koff);
            alf[i] = *(const halfx8*)(sAl + (arow + i * 16 + rr) * 32 + koff);
        }
        #pragma unroll
        for (int j = 0; j < FN; ++j) {
            bhf[j] = *(const halfx8*)(sBh + (brow + j * 16 + rr) * 32 + koff);
            blf[j] = *(const halfx8*)(sBl + (brow + j * 16 + rr) * 32 + koff);
        }
        #pragma unroll
        for (int i = 0; i < FM; ++i)
            #pragma unroll
            for (int j = 0; j < FN; ++j) {
                acc[i][j] = __builtin_amdgcn_mfma_f32_16x16x32_f16(ahf[i], bhf[j], acc[i][j], 0, 0, 0);
                acc[i][j] = __builtin_amdgcn_mfma_f32_16x16x32_f16(ahf[i], blf[j], acc[i][j], 0, 0, 0);
                acc[i][j] = __builtin_amdgcn_mfma_f32_16x16x32_f16(alf[i], bhf[j], acc[i][j], 0, 0, 0);
            }
        asm volatile("s_waitcnt lgkmcnt(0)" ::: "memory");   // ds_reads of bf complete
        __builtin_amdgcn_s_barrier();          // safe for next iter to overwrite bf
    }
}

// ---------------------------------------------------------------------------
// split all static operands to hi/lo fp16 (dtw padded K 48->64), float4/thread
__global__ __launch_bounds__(256) void k_splitall(
        const float* __restrict__ hs,  const float* __restrict__ wip,
        const float* __restrict__ wop, const float* __restrict__ xw,
        const float* __restrict__ dtw,
        _Float16* __restrict__ hsh,  _Float16* __restrict__ hsl,
        _Float16* __restrict__ wiph, _Float16* __restrict__ wipl,
        _Float16* __restrict__ woph, _Float16* __restrict__ wopl,
        _Float16* __restrict__ xwh,  _Float16* __restrict__ xwl,
        _Float16* __restrict__ dtwh, _Float16* __restrict__ dtwl) {
    int i4 = (blockIdx.x * 256 + threadIdx.x) * 4;
    floatx4 v;
    _Float16 *dh, *dl; int off;
    if (i4 < 786432)        { off = i4;           v = *(const floatx4*)(hs + off);  dh = hsh;  dl = hsl;  }
    else if (i4 < 3145728)  { off = i4 - 786432;  v = *(const floatx4*)(wip + off); dh = wiph; dl = wipl; }
    else if (i4 < 4325376)  { off = i4 - 3145728; v = *(const floatx4*)(wop + off); dh = woph; dl = wopl; }
    else if (i4 < 4816896)  { off = i4 - 4325376; v = *(const floatx4*)(xw + off);  dh = xwh;  dl = xwl;  }
    else {
        int t0 = i4 - 4816896;          // [dir*1536 + d][64] padded
        int col = t0 & 63, dr = t0 >> 6;
        floatx4 z = {0.f, 0.f, 0.f, 0.f};
        v = (col < 48) ? *(const floatx4*)(dtw + (size_t)dr * 48 + col) : z;
        dh = dtwh; dl = dtwl; off = t0;
    }
    halfx4 hh, hl;
    #pragma unroll
    for (int e = 0; e < 4; ++e) {
        _Float16 h = (_Float16)v[e];
        hh[e] = h; hl[e] = (_Float16)(v[e] - (float)h);
    }
    *(halfx4*)(dh + off) = hh;
    *(halfx4*)(dl + off) = hl;
}

// ---------------------------------------------------------------------------
// in_proj: (1024x768)*(3072x768)^T, 64x64 tile, split-K=1 -> SINGLE fp32
// plane. Grid 16x48 = 768 blocks = 3 blocks/CU (was 1.5 with 64x128) so
// barrier stalls overlap across blocks. VM=4 (2 A + 2 B loads/thread,
// uniform). LDS 32 KB.
__global__ __launch_bounds__(256) void k_inproj_t(const _Float16* __restrict__ Ah,
                                                  const _Float16* __restrict__ Al,
                                                  const _Float16* __restrict__ Bh,
                                                  const _Float16* __restrict__ Bl,
                                                  float* __restrict__ C) {
    __shared__ _Float16 smem[2 * 128 * 64];
    int row0 = blockIdx.x * 64, col0 = blockIdx.y * 64;
    floatx4 acc[2][2] = {};
    gemm_core<64, 64, 2, 2, 2, 4>(Ah + (size_t)row0 * EI, Al + (size_t)row0 * EI, EI,
                                  Bh + (size_t)col0 * EI, Bl + (size_t)col0 * EI, EI,
                                  24, smem, acc);
    int lane = threadIdx.x & 63, wave = threadIdx.x >> 6;
    int cc = lane & 15, q = lane >> 4;
    int rbase = row0 + (wave >> 1) * 32, cbase = col0 + (wave & 1) * 32;
    #pragma unroll
    for (int i = 0; i < 2; ++i)
        #pragma unroll
        for (int j = 0; j < 2; ++j)
            #pragma unroll
            for (int r = 0; r < 4; ++r)
                C[(size_t)(rbase + i * 16 + q * 4 + r) * F2D + cbase + j * 16 + cc] = acc[i][j][r];
}

// out_proj: (1024x1536)*(768x1536)^T, 64x64 tile, K-split x4 -> 4 planes.
// Grid 16x12x4 = 768 blocks = 3/CU (was 1.5). VM=4.
__global__ __launch_bounds__(256) void k_outproj_t(const _Float16* __restrict__ Ah,
                                                   const _Float16* __restrict__ Al,
                                                   const _Float16* __restrict__ Bh,
                                                   const _Float16* __restrict__ Bl,
                                                   float* __restrict__ C) {
    __shared__ _Float16 smem[2 * 128 * 64];
    int row0 = blockIdx.x * 64, col0 = blockIdx.y * 64, k0 = blockIdx.z * 384;
    float* Cp = C + (size_t)blockIdx.z * MROWS * EI;
    floatx4 acc[2][2] = {};
    gemm_core<64, 64, 2, 2, 2, 4>(Ah + (size_t)row0 * DI + k0, Al + (size_t)row0 * DI + k0, DI,
                                  Bh + (size_t)col0 * DI + k0, Bl + (size_t)col0 * DI + k0, DI,
                                  12, smem, acc);
    int lane = threadIdx.x & 63, wave = threadIdx.x >> 6;
    int cc = lane & 15, q = lane >> 4;
    int rbase = row0 + (wave >> 1) * 32, cbase = col0 + (wave & 1) * 32;
    #pragma unroll
    for (int i = 0; i < 2; ++i)
        #pragma unroll
        for (int j = 0; j < 2; ++j)
            #pragma unroll
            for (int r = 0; r < 4; ++r)
                Cp[(size_t)(rbase + i * 16 + q * 4 + r) * EI + cbase + j * 16 + cc] = acc[i][j][r];
}

// final out = sum of 4 out_proj partial planes
__global__ __launch_bounds__(256) void k_osum(const float* __restrict__ oacc,
                                              float* __restrict__ out) {
    int i4 = (blockIdx.x * 256 + threadIdx.x) * 4;
    const size_t S = (size_t)MROWS * EI;
    floatx4 s = *(const floatx4*)(oacc + i4) + *(const floatx4*)(oacc + S + i4) +
                *(const floatx4*)(oacc + 2 * S + i4) + *(const floatx4*)(oacc + 3 * S + i4);
    *(floatx4*)(out + i4) = s;
}

// x_dbl: per dir (1024x1536)*(80x1536)^T, 64-row tiles (512 blocks, 2/CU),
// K-split x8 -> 8 partial planes. VM=4: waves 1-3 issue 4 loads/chunk (wave 0
// issues 6 and over-waits 2 -- safe, min across waves).
__global__ __launch_bounds__(256) void k_xdbl_t(const _Float16* __restrict__ xh,
                                                const _Float16* __restrict__ xl,
                                                const _Float16* __restrict__ xwh,
                                                const _Float16* __restrict__ xwl,
                                                float* __restrict__ C) {
    __shared__ _Float16 smem[2 * 144 * 64];
    int row0 = blockIdx.x * 64, dir = blockIdx.y, k0 = blockIdx.z * 192;
    float* Cp = C + (size_t)blockIdx.z * NDIRS * MROWS * 80;
    floatx4 acc[1][5] = {};
    const size_t abase = ((size_t)dir * MROWS + row0) * DI + k0;
    const size_t bbase = (size_t)dir * 80 * DI + k0;
    gemm_core<64, 80, 1, 1, 5, 4>(xh + abase, xl + abase, DI,
                                  xwh + bbase, xwl + bbase, DI, 6, smem, acc);
    int lane = threadIdx.x & 63, wave = threadIdx.x >> 6;
    int cc = lane & 15, q = lane >> 4;
    int rbase = row0 + wave * 16;
    #pragma unroll
    for (int j = 0; j < 5; ++j)
        #pragma unroll
        for (int r = 0; r < 4; ++r)
            Cp[((size_t)dir * MROWS + rbase + q * 4 + r) * 80 + j * 16 + cc] = acc[0][j][r];
}

// xdbl epilogue: sum 8 partial planes; split cols -> dtq hi/lo (padded to 64),
// PAIRED (B0,B1,C0,C1) quads into BCm (pk-f32 friendly in k_scan).
// 96 cols per row (race-free mapping).
__global__ __launch_bounds__(256) void k_xsplit(const float* __restrict__ acc,
                                                _Float16* __restrict__ dtqh,
                                                _Float16* __restrict__ dtql,
                                                float* __restrict__ BCm) {
    const size_t PS = (size_t)NDIRS * MROWS * 80;
    int idx = blockIdx.x * 256 + threadIdx.x;   // < 4*1024*96
    int dir = idx / (MROWS * 96);
    int rem = idx - dir * MROWS * 96;
    int row = rem / 96, col = rem - row * 96;
    size_t rbase = (size_t)dir * MROWS + row;
    auto sum8 = [&](int c) {
        size_t o = rbase * 80 + c;
        float s = 0.f;
        #pragma unroll
        for (int kp = 0; kp < 8; ++kp) s += acc[kp * PS + o];
        return s;
    };
    if (col < 64) {
        float v = (col < 48) ? sum8(col) : 0.f;
        _Float16 h = (_Float16)v;
        dtqh[rbase * 64 + col] = h;
        dtql[rbase * 64 + col] = (_Float16)(v - (float)h);
    } else if (col < 80) {
        int n = col - 64;
        BCm[rbase * 32 + (n >> 1) * 4 + (n & 1)] = sum8(48 + n);       // B pair slots {0,1}
    } else {
        int n = col - 80;
        BCm[rbase * 32 + (n >> 1) * 4 + 2 + (n & 1)] = sum8(64 + n);   // C pair slots {2,3}
    }
}

// ---------------------------------------------------------------------------
// Fused 4-direction depthwise causal conv (K=4) + bias + silu.
// One block stages x[256 l][16 d] (single xz plane) in LDS ONCE,
// then computes all 4 directions from the tile (perm reads are LDS reads).
__global__ __launch_bounds__(512) void k_conv4(const float* __restrict__ xz,
                                               const float* __restrict__ cw,
                                               const float* __restrict__ cb,
                                               _Float16* __restrict__ xh,
                                               _Float16* __restrict__ xl) {
    const int b = blockIdx.y, d0 = blockIdx.x * 16;
    const int tid = threadIdx.x;
    __shared__ float sx[256][18];     // [l][d], 18 KB

    for (int i = tid; i < 1024; i += 512) {
        int row = i >> 2, c4 = (i & 3) * 4;
        size_t o = ((size_t)b * 256 + row) * F2D + d0 + c4;
        floatx4 v = *(const floatx4*)(xz + o);
        floatx2 v0 = {v[0], v[1]}, v1 = {v[2], v[3]};
        *(floatx2*)&sx[row][c4]     = v0;
        *(floatx2*)&sx[row][c4 + 2] = v1;
    }
    __syncthreads();

    const int dsub = tid & 15, lg = tid >> 4;    // 32 l-groups x 8 outputs
    const int d = d0 + dsub, j0 = lg * 8;
    #pragma unroll
    for (int dir = 0; dir < NDIRS; ++dir) {
        floatx4 w = *(const floatx4*)(cw + ((size_t)dir * DI + d) * KI);
        float bias = cb[(size_t)dir * DI + d];
        float xm3 = (j0 >= 3) ? sx[perm_idx(dir, j0 - 3)][dsub] : 0.f;
        float xm2 = (j0 >= 2) ? sx[perm_idx(dir, j0 - 2)][dsub] : 0.f;
        float xm1 = (j0 >= 1) ? sx[perm_idx(dir, j0 - 1)][dsub] : 0.f;
        #pragma unroll
        for (int j = 0; j < 8; ++j) {
            float cur = sx[perm_idx(dir, j0 + j)][dsub];
            float s = bias + w[0] * xm3 + w[1] * xm2 + w[2] * xm1 + w[3] * cur;
            xm3 = xm2; xm2 = xm1; xm1 = cur;
            float x = s / (1.f + __expf(-s));
            _Float16 h = (_Float16)x;
            size_t o = ((size_t)dir * MROWS + b * 256 + j0 + j) * DI + d;
            xh[o] = h;
            xl[o] = (_Float16)(x - (float)h);
        }
    }
}

// ---------------------------------------------------------------------------
// Selective scan v10: v8r structure (single barrier/chunk, double-buffered
// LDS, fused MFMA delta, setprio around R) + PACKED-fp32 recurrence:
// BCm quads are {B0,B1,C0,C1} so B-pair/C-pair are register-aligned; h
// updates via v_pk_fma_f32 (floatx2 + __builtin_elementwise_fma).
// ---------------------------------------------------------------------------
__global__ __launch_bounds__(256) void k_scan(const _Float16* __restrict__ dtqh,
                                              const _Float16* __restrict__ dtql,
                                              const _Float16* __restrict__ dtwh,
                                              const _Float16* __restrict__ dtwl,
                                              const float* __restrict__ dtb,
                                              const _Float16* __restrict__ xhg,
                                              const _Float16* __restrict__ xlg,
                                              const float* __restrict__ BCm,
                                              const float* __restrict__ A_log,
                                              const float* __restrict__ Dp,
                                              float* __restrict__ ydir) {
    const int dchunk = blockIdx.x, b = blockIdx.y, dir = blockIdx.z;
    const int tid = threadIdx.x, lane = tid & 63, wave = tid >> 6;
    const int dslot = tid >> 3;        // 0..31
    const int np = tid & 7;            // n-pair index
    const int d0 = dchunk * 32, d = d0 + dslot;

    __shared__ float sdx[2][32][68];   // [buf][d][jj*2 + {0:delta,1:x}]
    __shared__ float sbc[2][32][32];   // [buf][jj][np*4 + {B0,B1,C0,C1}]
    __shared__ float sY[2][32][32];

    const floatx2 Av = {
        -__expf(A_log[((size_t)dir * DI + d) * NI + 2 * np]) * LOG2E,
        -__expf(A_log[((size_t)dir * DI + d) * NI + 2 * np + 1]) * LOG2E };
    const float Dpar = Dp[(size_t)dir * DI + d];
    floatx2 h = {0.f, 0.f};

    const size_t dirrow = (size_t)dir * MROWS;
    const int srow = tid >> 3, sc4 = (tid & 7) * 4;   // staging roles

    // ---- MFMA roles: wave -> (rowhalf, dhalf); same fragment layout as gemm_core
    const int rowhalf = wave >> 1, dhalf = wave & 1;
    const int rr = lane & 15, koff = (lane >> 4) * 8, q = lane >> 4;
    const size_t bfb = ((size_t)dir * DI + d0 + dhalf * 16 + rr) * 64;
    halfx8 bhf[2], blf[2];
    bhf[0] = *(const halfx8*)(dtwh + bfb + koff);
    bhf[1] = *(const halfx8*)(dtwh + bfb + 32 + koff);
    blf[0] = *(const halfx8*)(dtwl + bfb + koff);
    blf[1] = *(const halfx8*)(dtwl + bfb + 32 + koff);
    const float bias = dtb[(size_t)dir * DI + d0 + dhalf * 16 + rr];

    floatx4 rbc;
    halfx4 rxh, rxl;
    auto load_chunk = [&](int j0) {
        int row = b * 256 + j0 + srow;
        size_t o = (dirrow + row) * DI + d0 + sc4;
        rxh = *(const halfx4*)(xhg + o);
        rxl = *(const halfx4*)(xlg + o);
        rbc = *(const floatx4*)(BCm + (dirrow + row) * 32 + sc4);
    };
    halfx8 ahf[2], alf[2];
    auto load_afrag = [&](int c) {
        size_t o = (dirrow + b * 256 + c * 32 + rowhalf * 16 + rr) * 64;
        ahf[0] = *(const halfx8*)(dtqh + o + koff);
        ahf[1] = *(const halfx8*)(dtqh + o + 32 + koff);
        alf[0] = *(const halfx8*)(dtql + o + koff);
        alf[1] = *(const halfx8*)(dtql + o + 32 + koff);
    };
    auto stage = [&](int bf) {
        #pragma unroll
        for (int e = 0; e < 4; ++e)
            sdx[bf][sc4 + e][srow * 2 + 1] = (float)rxh[e] + (float)rxl[e];
        *(floatx4*)&sbc[bf][srow][sc4] = rbc;
    };
    auto mfma_delta = [&](int bf) {
        floatx4 acc = {};
        #pragma unroll
        for (int kc = 0; kc < 2; ++kc) {
            acc = __builtin_amdgcn_mfma_f32_16x16x32_f16(ahf[kc], bhf[kc], acc, 0, 0, 0);
            acc = __builtin_amdgcn_mfma_f32_16x16x32_f16(ahf[kc], blf[kc], acc, 0, 0, 0);
            acc = __builtin_amdgcn_mfma_f32_16x16x32_f16(alf[kc], bhf[kc], acc, 0, 0, 0);
        }
        #pragma unroll
        for (int r = 0; r < 4; ++r) {
            float v = acc[r] + bias;
            float sp = (v > 20.f) ? v
                     : __log2f(1.f + __builtin_amdgcn_exp2f(v * LOG2E)) * LN2;
            sdx[bf][dhalf * 16 + rr][(rowhalf * 16 + q * 4 + r) * 2] = sp;
        }
    };

    // prologue: chunk 0 staged + delta'd, chunk-1 loads in flight
    load_chunk(0);
    load_afrag(0);
    stage(0);
    mfma_delta(0);
    load_chunk(32);
    load_afrag(1);
    __syncthreads();

    for (int c = 0; c < 8; ++c) {
        const int buf = c & 1;
        // ---- overlap phase: next chunk's stage + delta + loads for c+2 ----
        if (c < 7) {
            stage(buf ^ 1);
            mfma_delta(buf ^ 1);
            if (c < 6) { load_chunk((c + 2) * 32); load_afrag(c + 2); }
        }

        // ---- R(c): 32 recurrence steps, 2 per dx b128, packed-fp32 math ----
        __builtin_amdgcn_s_setprio(1);
        #pragma unroll
        for (int jj = 0; jj < 32; jj += 2) {
            floatx4 dxx = *(const floatx4*)&sdx[buf][dslot][jj * 2];
            #pragma unroll
            for (int t = 0; t < 2; ++t) {
                floatx4 bc = *(const floatx4*)&sbc[buf][jj + t][np * 4];  // B0,B1,C0,C1
                float dv = dxx[t * 2], xv = dxx[t * 2 + 1];
                floatx2 tt = Av * dv;                          // v_pk_mul_f32
                floatx2 a = { __builtin_amdgcn_exp2f(tt[0]),
                              __builtin_amdgcn_exp2f(tt[1]) };
                float du = dv * xv;
                floatx2 Bp = { bc[0], bc[1] };
                floatx2 Cp = { bc[2], bc[3] };
                h = __builtin_elementwise_fma(a, h, Bp * du);  // pk_mul + pk_fma
                floatx2 qv = h * Cp;                           // v_pk_mul_f32
                float p = qv[0] + qv[1];
                p = grp8_sum(p);
                if (np == 0) sY[buf][jj + t][dslot] = fmaf(Dpar, xv, p);
            }
        }
        __builtin_amdgcn_s_setprio(0);
        __syncthreads();                       // sY[buf] complete; buf^1 staged

        // ---- W(c): ungated write to out-domain (4 floats/thread, 128B rows) ----
        {
            int lout = perm_idx(dir, c * 32 + srow);
            floatx4 o = *(const floatx4*)&sY[buf][srow][sc4];
            *(floatx4*)&ydir[(dirrow + (size_t)b * 256 + lout) * DI + d0 + sc4] = o;
        }
    }
}

// sum of 4 direction outputs, gate by silu(z) -> hi/lo fp16 for out_proj
__global__ __launch_bounds__(256) void k_sum(const float* __restrict__ ydir,
                                             const float* __restrict__ xz,
                                             _Float16* __restrict__ yh,
                                             _Float16* __restrict__ yl) {
    int i4 = (blockIdx.x * 256 + threadIdx.x) * 4;
    const size_t S = (size_t)MROWS * DI;
    int row = i4 / DI, dcol = i4 - row * DI;
    size_t zo = (size_t)row * F2D + DI + dcol;
    floatx4 zv = *(const floatx4*)(xz + zo);
    floatx4 s = *(const floatx4*)(ydir + i4) + *(const floatx4*)(ydir + S + i4) +
                *(const floatx4*)(ydir + 2 * S + i4) + *(const floatx4*)(ydir + 3 * S + i4);
    halfx4 hh, hl;
    #pragma unroll
    for (int e = 0; e < 4; ++e) {
        float g = zv[e] / (1.f + __expf(-zv[e]));
        float v = s[e] * g;
        _Float16 h = (_Float16)v;
        hh[e] = h; hl[e] = (_Float16)(v - (float)h);
    }
    *(halfx4*)(yh + i4) = hh;
    *(halfx4*)(yl + i4) = hl;
}

// ---------------------------------------------------------------------------
extern "C" void kernel_launch(void* const* d_in, const int* in_sizes, int n_in,
                              void* d_out, int out_size, void* d_ws, size_t ws_size,
                              hipStream_t stream) {
    const float* hs   = (const float*)d_in[0];
    const float* wip  = (const float*)d_in[1];
    const float* wop  = (const float*)d_in[2];
    const float* cw   = (const float*)d_in[3];
    const float* cb   = (const float*)d_in[4];
    const float* xw   = (const float*)d_in[5];
    const float* dtw  = (const float*)d_in[6];
    const float* dtb  = (const float*)d_in[7];
    const float* alog = (const float*)d_in[8];
    const float* dpar = (const float*)d_in[9];
    float* out = (float*)d_out;

    char* p = (char*)d_ws;
    auto alloc_f32 = [&](size_t n) { float* r = (float*)p; p += n * 4; return r; };
    auto alloc_f16 = [&](size_t n) { _Float16* r = (_Float16*)p; p += n * 2; return r; };

    _Float16* hsh  = alloc_f16(786432);
    _Float16* hsl  = alloc_f16(786432);
    _Float16* wiph = alloc_f16(2359296);
    _Float16* wipl = alloc_f16(2359296);
    _Float16* woph = alloc_f16(1179648);
    _Float16* wopl = alloc_f16(1179648);
    _Float16* xwh  = alloc_f16(491520);
    _Float16* xwl  = alloc_f16(491520);
    _Float16* dtwh = alloc_f16((size_t)NDIRS * DI * 64);
    _Float16* dtwl = alloc_f16((size_t)NDIRS * DI * 64);
    float*    xz   = alloc_f32((size_t)MROWS * F2D);       // single plane
    _Float16* xh   = alloc_f16((size_t)NDIRS * MROWS * DI);
    _Float16* xl   = alloc_f16((size_t)NDIRS * MROWS * DI);
    _Float16* dtqh = alloc_f16((size_t)NDIRS * MROWS * 64);
    _Float16* dtql = alloc_f16((size_t)NDIRS * MROWS * 64);
    float*    BCm  = alloc_f32((size_t)NDIRS * MROWS * 32);
    float*    oacc = alloc_f32((size_t)4 * MROWS * EI);    // outproj 4 planes
    float*    ydir = alloc_f32((size_t)NDIRS * MROWS * DI);
    _Float16* yh   = alloc_f16((size_t)MROWS * DI);
    _Float16* yl   = alloc_f16((size_t)MROWS * DI);

    // alias onto dead region (disjoint lifetimes):
    float* xdba = ydir;    // xdbl 8 planes (10.5 MB <= 25.2 MB); dead after k_xsplit

    k_splitall<<<dim3(5088), 256, 0, stream>>>(hs, wip, wop, xw, dtw,
                                               hsh, hsl, wiph, wipl, woph, wopl,
                                               xwh, xwl, dtwh, dtwl);
    k_inproj_t<<<dim3(16, 48), 256, 0, stream>>>(hsh, hsl, wiph, wipl, xz);
    k_conv4   <<<dim3(96, BI), 512, 0, stream>>>(xz, cw, cb, xh, xl);
    k_xdbl_t  <<<dim3(16, NDIRS, 8), 256, 0, stream>>>(xh, xl, xwh, xwl, xdba);
    k_xsplit  <<<dim3(1536), 256, 0, stream>>>(xdba, dtqh, dtql, BCm);
    k_scan    <<<dim3(DI / 32, BI, NDIRS), 256, 0, stream>>>(dtqh, dtql, dtwh, dtwl, dtb,
                                                             xh, xl, BCm, alog, dpar, ydir);
    k_sum     <<<dim3(1536), 256, 0, stream>>>(ydir, xz, yh, yl);
    k_outproj_t<<<dim3(16, 12, 4), 256, 0, stream>>>(yh, yl, woph, wopl, oacc);
    k_osum    <<<dim3(768), 256, 0, stream>>>(oacc, out);
}

// Round 10
// 197.745 us; speedup vs baseline: 1.0264x; 1.0264x over previous
//
#include <hip/hip_runtime.h>
#include <hip/hip_bf16.h>

#define BI   4
#define LI   256
#define EI   768
#define DI   1536
#define NI   16
#define RI   48
#define KI   4
#define NDIRS 4
#define F2D  3072              // 2*D
#define MROWS 1024             // B*L
#define LOG2E 1.4426950408889634f
#define LN2   0.6931471805599453f

typedef float    floatx2 __attribute__((ext_vector_type(2)));
typedef float    floatx4 __attribute__((ext_vector_type(4)));
typedef _Float16 halfx2  __attribute__((ext_vector_type(2)));
typedef _Float16 halfx4  __attribute__((ext_vector_type(4)));
typedef _Float16 halfx8  __attribute__((ext_vector_type(8)));

typedef __attribute__((address_space(3))) unsigned lds_u32;
typedef __attribute__((address_space(1))) const unsigned glb_u32;

__device__ __forceinline__ void load16(const _Float16* g, _Float16* l) {
    __builtin_amdgcn_global_load_lds((glb_u32*)g, (lds_u32*)l, 16, 0, 0);
}

__device__ __forceinline__ int perm_idx(int dir, int j) {
    switch (dir) {
        case 0:  return j;
        case 1:  return 255 - j;
        case 2:  return ((j & 15) << 4) | (j >> 4);
        default: return 255 - (((j & 15) << 4) | (j >> 4));
    }
}

// DPP-based add of a permuted copy (VALU pipe, no LDS traffic).
template<int CTRL>
__device__ __forceinline__ float dpp_add(float p) {
    int t = __builtin_amdgcn_update_dpp(0, __builtin_bit_cast(int, p),
                                        CTRL, 0xf, 0xf, true);
    return p + __builtin_bit_cast(float, t);
}
// sum over 8 consecutive lanes (tid&7 group)
__device__ __forceinline__ float grp8_sum(float p) {
    p = dpp_add<0xB1>(p);    // quad_perm [1,0,3,2]  : xor 1
    p = dpp_add<0x4E>(p);    // quad_perm [2,3,0,1]  : xor 2
    p = dpp_add<0x141>(p);   // row_half_mirror      : combine quads
    return p;
}

// ---------------------------------------------------------------------------
// Tiled hi/lo-fp16 GEMM core, COUNTED-VMCNT 2-phase pipeline: per chunk
// {issue stage(c+1) -> s_waitcnt vmcnt(VM) [own c-loads done] -> s_barrier ->
// ds_read+MFMA -> lgkmcnt(0) -> s_barrier}. Loads for c+1 stay in flight
// across the whole compute of c. VM = per-wave loads issued per stage (min
// across waves when non-uniform). smem = 2x(BM+BN)*64 halfs.
// ---------------------------------------------------------------------------
template<int BM, int BN, int WGN, int FM, int FN, int VM>
__device__ __forceinline__ void gemm_core(const _Float16* __restrict__ Ah,
                                          const _Float16* __restrict__ Al, int lda,
                                          const _Float16* __restrict__ Bh,
                                          const _Float16* __restrict__ Bl, int ldb,
                                          int nChunks, _Float16* smem,
                                          floatx4 (&acc)[FM][FN]) {
    const int tid = threadIdx.x, lane = tid & 63, wave = tid >> 6;
    const int wave_m = wave / WGN, wave_n = wave % WGN;
    const int rr = lane & 15, koff = (lane >> 4) * 8;
    const int arow = wave_m * FM * 16, brow = wave_n * FN * 16;
    constexpr int BUFSZ = (BM + BN) * 64;

    auto stage = [&](int c, int bf) {
        _Float16* sAh = smem + bf * BUFSZ;
        _Float16* sAl = sAh + BM * 32;
        _Float16* sBh = sAh + BM * 64;
        _Float16* sBl = sAh + BM * 64 + BN * 32;
        for (int idx = tid; idx < BM * 4; idx += 256) {
            int r = idx >> 2, s = (idx & 3) * 8;
            load16(Ah + (size_t)r * lda + c * 32 + s, sAh + idx * 8);
            load16(Al + (size_t)r * lda + c * 32 + s, sAl + idx * 8);
        }
        for (int idx = tid; idx < BN * 4; idx += 256) {
            int r = idx >> 2, s = (idx & 3) * 8;
            load16(Bh + (size_t)r * ldb + c * 32 + s, sBh + idx * 8);
            load16(Bl + (size_t)r * ldb + c * 32 + s, sBl + idx * 8);
        }
    };

    stage(0, 0);

    for (int c = 0; c < nChunks; ++c) {
        const int bf = c & 1;
        if (c + 1 < nChunks) {
            stage(c + 1, bf ^ 1);              // issue-early into the other buffer
            asm volatile("s_waitcnt vmcnt(%0)" :: "n"(VM) : "memory");  // own c-loads done
        } else {
            asm volatile("s_waitcnt vmcnt(0)" ::: "memory");
        }
        __builtin_amdgcn_s_barrier();          // all waves' c-loads landed

        const _Float16* sAh = smem + bf * BUFSZ;
        const _Float16* sAl = sAh + BM * 32;
        const _Float16* sBh = sAh + BM * 64;
        const _Float16* sBl = sAh + BM * 64 + BN * 32;
        halfx8 ahf[FM], alf[FM], bhf[FN], blf[FN];
        #pragma unroll
        for (int i = 0; i < FM; ++i) {
            ahf[i] = *(const halfx8*)(sAh + (arow + i * 16 + rr) * 32 + koff);
            alf[i] = *(const halfx8*)(sAl + (arow + i * 16 + rr) * 32 + koff);
        }
        #pragma unroll
        for (int j = 0; j < FN; ++j) {
            bhf[j] = *(const halfx8*)(sBh + (brow + j * 16 + rr) * 32 + koff);
            blf[j] = *(const halfx8*)(sBl + (brow + j * 16 + rr) * 32 + koff);
        }
        #pragma unroll
        for (int i = 0; i < FM; ++i)
            #pragma unroll
            for (int j = 0; j < FN; ++j) {
                acc[i][j] = __builtin_amdgcn_mfma_f32_16x16x32_f16(ahf[i], bhf[j], acc[i][j], 0, 0, 0);
                acc[i][j] = __builtin_amdgcn_mfma_f32_16x16x32_f16(ahf[i], blf[j], acc[i][j], 0, 0, 0);
                acc[i][j] = __builtin_amdgcn_mfma_f32_16x16x32_f16(alf[i], bhf[j], acc[i][j], 0, 0, 0);
            }
        asm volatile("s_waitcnt lgkmcnt(0)" ::: "memory");   // ds_reads of bf complete
        __builtin_amdgcn_s_barrier();          // safe for next iter to overwrite bf
    }
}

// ---------------------------------------------------------------------------
// split all static operands to hi/lo fp16 (dtw padded K 48->64), float4/thread
__global__ __launch_bounds__(256) void k_splitall(
        const float* __restrict__ hs,  const float* __restrict__ wip,
        const float* __restrict__ wop, const float* __restrict__ xw,
        const float* __restrict__ dtw,
        _Float16* __restrict__ hsh,  _Float16* __restrict__ hsl,
        _Float16* __restrict__ wiph, _Float16* __restrict__ wipl,
        _Float16* __restrict__ woph, _Float16* __restrict__ wopl,
        _Float16* __restrict__ xwh,  _Float16* __restrict__ xwl,
        _Float16* __restrict__ dtwh, _Float16* __restrict__ dtwl) {
    int i4 = (blockIdx.x * 256 + threadIdx.x) * 4;
    floatx4 v;
    _Float16 *dh, *dl; int off;
    if (i4 < 786432)        { off = i4;           v = *(const floatx4*)(hs + off);  dh = hsh;  dl = hsl;  }
    else if (i4 < 3145728)  { off = i4 - 786432;  v = *(const floatx4*)(wip + off); dh = wiph; dl = wipl; }
    else if (i4 < 4325376)  { off = i4 - 3145728; v = *(const floatx4*)(wop + off); dh = woph; dl = wopl; }
    else if (i4 < 4816896)  { off = i4 - 4325376; v = *(const floatx4*)(xw + off);  dh = xwh;  dl = xwl;  }
    else {
        int t0 = i4 - 4816896;          // [dir*1536 + d][64] padded
        int col = t0 & 63, dr = t0 >> 6;
        floatx4 z = {0.f, 0.f, 0.f, 0.f};
        v = (col < 48) ? *(const floatx4*)(dtw + (size_t)dr * 48 + col) : z;
        dh = dtwh; dl = dtwl; off = t0;
    }
    halfx4 hh, hl;
    #pragma unroll
    for (int e = 0; e < 4; ++e) {
        _Float16 h = (_Float16)v[e];
        hh[e] = h; hl[e] = (_Float16)(v[e] - (float)h);
    }
    *(halfx4*)(dh + off) = hh;
    *(halfx4*)(dl + off) = hl;
}

// ---------------------------------------------------------------------------
// in_proj: (1024x768)*(3072x768)^T, 64x128 tile, split-K=1 -> SINGLE fp32
// plane. Grid 16x24 = 384 blocks, counted-vmcnt dbuf (VM=6). [round-8 best]
__global__ __launch_bounds__(256) void k_inproj_t(const _Float16* __restrict__ Ah,
                                                  const _Float16* __restrict__ Al,
                                                  const _Float16* __restrict__ Bh,
                                                  const _Float16* __restrict__ Bl,
                                                  float* __restrict__ C) {
    __shared__ _Float16 smem[2 * 192 * 64];
    int row0 = blockIdx.x * 64, col0 = blockIdx.y * 128;
    floatx4 acc[2][4] = {};
    gemm_core<64, 128, 2, 2, 4, 6>(Ah + (size_t)row0 * EI, Al + (size_t)row0 * EI, EI,
                                   Bh + (size_t)col0 * EI, Bl + (size_t)col0 * EI, EI,
                                   24, smem, acc);
    int lane = threadIdx.x & 63, wave = threadIdx.x >> 6;
    int cc = lane & 15, q = lane >> 4;
    int rbase = row0 + (wave >> 1) * 32, cbase = col0 + (wave & 1) * 64;
    #pragma unroll
    for (int i = 0; i < 2; ++i)
        #pragma unroll
        for (int j = 0; j < 4; ++j)
            #pragma unroll
            for (int r = 0; r < 4; ++r)
                C[(size_t)(rbase + i * 16 + q * 4 + r) * F2D + cbase + j * 16 + cc] = acc[i][j][r];
}

// out_proj: (1024x1536)*(768x1536)^T, 64x128 tile, K-split x4 -> 4 planes.
// [round-8 best]
__global__ __launch_bounds__(256) void k_outproj_t(const _Float16* __restrict__ Ah,
                                                   const _Float16* __restrict__ Al,
                                                   const _Float16* __restrict__ Bh,
                                                   const _Float16* __restrict__ Bl,
                                                   float* __restrict__ C) {
    __shared__ _Float16 smem[2 * 192 * 64];
    int row0 = blockIdx.x * 64, col0 = blockIdx.y * 128, k0 = blockIdx.z * 384;
    float* Cp = C + (size_t)blockIdx.z * MROWS * EI;
    floatx4 acc[2][4] = {};
    gemm_core<64, 128, 2, 2, 4, 6>(Ah + (size_t)row0 * DI + k0, Al + (size_t)row0 * DI + k0, DI,
                                   Bh + (size_t)col0 * DI + k0, Bl + (size_t)col0 * DI + k0, DI,
                                   12, smem, acc);
    int lane = threadIdx.x & 63, wave = threadIdx.x >> 6;
    int cc = lane & 15, q = lane >> 4;
    int rbase = row0 + (wave >> 1) * 32, cbase = col0 + (wave & 1) * 64;
    #pragma unroll
    for (int i = 0; i < 2; ++i)
        #pragma unroll
        for (int j = 0; j < 4; ++j)
            #pragma unroll
            for (int r = 0; r < 4; ++r)
                Cp[(size_t)(rbase + i * 16 + q * 4 + r) * EI + cbase + j * 16 + cc] = acc[i][j][r];
}

// final out = sum of 4 out_proj partial planes
__global__ __launch_bounds__(256) void k_osum(const float* __restrict__ oacc,
                                              float* __restrict__ out) {
    int i4 = (blockIdx.x * 256 + threadIdx.x) * 4;
    const size_t S = (size_t)MROWS * EI;
    floatx4 s = *(const floatx4*)(oacc + i4) + *(const floatx4*)(oacc + S + i4) +
                *(const floatx4*)(oacc + 2 * S + i4) + *(const floatx4*)(oacc + 3 * S + i4);
    *(floatx4*)(out + i4) = s;
}

// x_dbl: per dir (1024x1536)*(80x1536)^T, 64-row tiles (512 blocks, 2/CU),
// K-split x8 -> 8 partial planes. VM=4 (min across waves).
__global__ __launch_bounds__(256) void k_xdbl_t(const _Float16* __restrict__ xh,
                                                const _Float16* __restrict__ xl,
                                                const _Float16* __restrict__ xwh,
                                                const _Float16* __restrict__ xwl,
                                                float* __restrict__ C) {
    __shared__ _Float16 smem[2 * 144 * 64];
    int row0 = blockIdx.x * 64, dir = blockIdx.y, k0 = blockIdx.z * 192;
    float* Cp = C + (size_t)blockIdx.z * NDIRS * MROWS * 80;
    floatx4 acc[1][5] = {};
    const size_t abase = ((size_t)dir * MROWS + row0) * DI + k0;
    const size_t bbase = (size_t)dir * 80 * DI + k0;
    gemm_core<64, 80, 1, 1, 5, 4>(xh + abase, xl + abase, DI,
                                  xwh + bbase, xwl + bbase, DI, 6, smem, acc);
    int lane = threadIdx.x & 63, wave = threadIdx.x >> 6;
    int cc = lane & 15, q = lane >> 4;
    int rbase = row0 + wave * 16;
    #pragma unroll
    for (int j = 0; j < 5; ++j)
        #pragma unroll
        for (int r = 0; r < 4; ++r)
            Cp[((size_t)dir * MROWS + rbase + q * 4 + r) * 80 + j * 16 + cc] = acc[0][j][r];
}

// xdbl epilogue: sum 8 partial planes; split cols -> dtq hi/lo (padded to 64),
// PAIRED (B0,B1,C0,C1) quads into BCm (pk-f32 friendly in k_scan).
__global__ __launch_bounds__(256) void k_xsplit(const float* __restrict__ acc,
                                                _Float16* __restrict__ dtqh,
                                                _Float16* __restrict__ dtql,
                                                float* __restrict__ BCm) {
    const size_t PS = (size_t)NDIRS * MROWS * 80;
    int idx = blockIdx.x * 256 + threadIdx.x;   // < 4*1024*96
    int dir = idx / (MROWS * 96);
    int rem = idx - dir * MROWS * 96;
    int row = rem / 96, col = rem - row * 96;
    size_t rbase = (size_t)dir * MROWS + row;
    auto sum8 = [&](int c) {
        size_t o = rbase * 80 + c;
        float s = 0.f;
        #pragma unroll
        for (int kp = 0; kp < 8; ++kp) s += acc[kp * PS + o];
        return s;
    };
    if (col < 64) {
        float v = (col < 48) ? sum8(col) : 0.f;
        _Float16 h = (_Float16)v;
        dtqh[rbase * 64 + col] = h;
        dtql[rbase * 64 + col] = (_Float16)(v - (float)h);
    } else if (col < 80) {
        int n = col - 64;
        BCm[rbase * 32 + (n >> 1) * 4 + (n & 1)] = sum8(48 + n);       // B pair slots {0,1}
    } else {
        int n = col - 80;
        BCm[rbase * 32 + (n >> 1) * 4 + 2 + (n & 1)] = sum8(64 + n);   // C pair slots {2,3}
    }
}

// ---------------------------------------------------------------------------
// Fused 4-direction depthwise causal conv (K=4) + bias + silu.
__global__ __launch_bounds__(512) void k_conv4(const float* __restrict__ xz,
                                               const float* __restrict__ cw,
                                               const float* __restrict__ cb,
                                               _Float16* __restrict__ xh,
                                               _Float16* __restrict__ xl) {
    const int b = blockIdx.y, d0 = blockIdx.x * 16;
    const int tid = threadIdx.x;
    __shared__ float sx[256][18];     // [l][d], 18 KB

    for (int i = tid; i < 1024; i += 512) {
        int row = i >> 2, c4 = (i & 3) * 4;
        size_t o = ((size_t)b * 256 + row) * F2D + d0 + c4;
        floatx4 v = *(const floatx4*)(xz + o);
        floatx2 v0 = {v[0], v[1]}, v1 = {v[2], v[3]};
        *(floatx2*)&sx[row][c4]     = v0;
        *(floatx2*)&sx[row][c4 + 2] = v1;
    }
    __syncthreads();

    const int dsub = tid & 15, lg = tid >> 4;    // 32 l-groups x 8 outputs
    const int d = d0 + dsub, j0 = lg * 8;
    #pragma unroll
    for (int dir = 0; dir < NDIRS; ++dir) {
        floatx4 w = *(const floatx4*)(cw + ((size_t)dir * DI + d) * KI);
        float bias = cb[(size_t)dir * DI + d];
        float xm3 = (j0 >= 3) ? sx[perm_idx(dir, j0 - 3)][dsub] : 0.f;
        float xm2 = (j0 >= 2) ? sx[perm_idx(dir, j0 - 2)][dsub] : 0.f;
        float xm1 = (j0 >= 1) ? sx[perm_idx(dir, j0 - 1)][dsub] : 0.f;
        #pragma unroll
        for (int j = 0; j < 8; ++j) {
            float cur = sx[perm_idx(dir, j0 + j)][dsub];
            float s = bias + w[0] * xm3 + w[1] * xm2 + w[2] * xm1 + w[3] * cur;
            xm3 = xm2; xm2 = xm1; xm1 = cur;
            float x = s / (1.f + __expf(-s));
            _Float16 h = (_Float16)x;
            size_t o = ((size_t)dir * MROWS + b * 256 + j0 + j) * DI + d;
            xh[o] = h;
            xl[o] = (_Float16)(x - (float)h);
        }
    }
}

// ---------------------------------------------------------------------------
// Selective scan v11: v10 structure + REGISTER-BATCHED R loop: 4 groups of 8
// steps; per group prefetch 4 dxx + 8 bc b128 into registers (12 back-to-back
// ds_reads, one lgkm wait), 8 steps pure-register math, sY writes deferred to
// group end (reads no longer serialized against predicated ds_writes).
// VGPR 52 -> ~110 (occupancy grid-capped at 3 blocks/CU, limit 170).
// ---------------------------------------------------------------------------
__global__ __launch_bounds__(256) void k_scan(const _Float16* __restrict__ dtqh,
                                              const _Float16* __restrict__ dtql,
                                              const _Float16* __restrict__ dtwh,
                                              const _Float16* __restrict__ dtwl,
                                              const float* __restrict__ dtb,
                                              const _Float16* __restrict__ xhg,
                                              const _Float16* __restrict__ xlg,
                                              const float* __restrict__ BCm,
                                              const float* __restrict__ A_log,
                                              const float* __restrict__ Dp,
                                              float* __restrict__ ydir) {
    const int dchunk = blockIdx.x, b = blockIdx.y, dir = blockIdx.z;
    const int tid = threadIdx.x, lane = tid & 63, wave = tid >> 6;
    const int dslot = tid >> 3;        // 0..31
    const int np = tid & 7;            // n-pair index
    const int d0 = dchunk * 32, d = d0 + dslot;

    __shared__ float sdx[2][32][68];   // [buf][d][jj*2 + {0:delta,1:x}]
    __shared__ float sbc[2][32][32];   // [buf][jj][np*4 + {B0,B1,C0,C1}]
    __shared__ float sY[2][32][32];

    const floatx2 Av = {
        -__expf(A_log[((size_t)dir * DI + d) * NI + 2 * np]) * LOG2E,
        -__expf(A_log[((size_t)dir * DI + d) * NI + 2 * np + 1]) * LOG2E };
    const float Dpar = Dp[(size_t)dir * DI + d];
    floatx2 h = {0.f, 0.f};

    const size_t dirrow = (size_t)dir * MROWS;
    const int srow = tid >> 3, sc4 = (tid & 7) * 4;   // staging roles

    // ---- MFMA roles: wave -> (rowhalf, dhalf); same fragment layout as gemm_core
    const int rowhalf = wave >> 1, dhalf = wave & 1;
    const int rr = lane & 15, koff = (lane >> 4) * 8, q = lane >> 4;
    const size_t bfb = ((size_t)dir * DI + d0 + dhalf * 16 + rr) * 64;
    halfx8 bhf[2], blf[2];
    bhf[0] = *(const halfx8*)(dtwh + bfb + koff);
    bhf[1] = *(const halfx8*)(dtwh + bfb + 32 + koff);
    blf[0] = *(const halfx8*)(dtwl + bfb + koff);
    blf[1] = *(const halfx8*)(dtwl + bfb + 32 + koff);
    const float bias = dtb[(size_t)dir * DI + d0 + dhalf * 16 + rr];

    floatx4 rbc;
    halfx4 rxh, rxl;
    auto load_chunk = [&](int j0) {
        int row = b * 256 + j0 + srow;
        size_t o = (dirrow + row) * DI + d0 + sc4;
        rxh = *(const halfx4*)(xhg + o);
        rxl = *(const halfx4*)(xlg + o);
        rbc = *(const floatx4*)(BCm + (dirrow + row) * 32 + sc4);
    };
    halfx8 ahf[2], alf[2];
    auto load_afrag = [&](int c) {
        size_t o = (dirrow + b * 256 + c * 32 + rowhalf * 16 + rr) * 64;
        ahf[0] = *(const halfx8*)(dtqh + o + koff);
        ahf[1] = *(const halfx8*)(dtqh + o + 32 + koff);
        alf[0] = *(const halfx8*)(dtql + o + koff);
        alf[1] = *(const halfx8*)(dtql + o + 32 + koff);
    };
    auto stage = [&](int bf) {
        #pragma unroll
        for (int e = 0; e < 4; ++e)
            sdx[bf][sc4 + e][srow * 2 + 1] = (float)rxh[e] + (float)rxl[e];
        *(floatx4*)&sbc[bf][srow][sc4] = rbc;
    };
    auto mfma_delta = [&](int bf) {
        floatx4 acc = {};
        #pragma unroll
        for (int kc = 0; kc < 2; ++kc) {
            acc = __builtin_amdgcn_mfma_f32_16x16x32_f16(ahf[kc], bhf[kc], acc, 0, 0, 0);
            acc = __builtin_amdgcn_mfma_f32_16x16x32_f16(ahf[kc], blf[kc], acc, 0, 0, 0);
            acc = __builtin_amdgcn_mfma_f32_16x16x32_f16(alf[kc], bhf[kc], acc, 0, 0, 0);
        }
        #pragma unroll
        for (int r = 0; r < 4; ++r) {
            float v = acc[r] + bias;
            float sp = (v > 20.f) ? v
                     : __log2f(1.f + __builtin_amdgcn_exp2f(v * LOG2E)) * LN2;
            sdx[bf][dhalf * 16 + rr][(rowhalf * 16 + q * 4 + r) * 2] = sp;
        }
    };

    // prologue: chunk 0 staged + delta'd, chunk-1 loads in flight
    load_chunk(0);
    load_afrag(0);
    stage(0);
    mfma_delta(0);
    load_chunk(32);
    load_afrag(1);
    __syncthreads();

    for (int c = 0; c < 8; ++c) {
        const int buf = c & 1;
        // ---- overlap phase: next chunk's stage + delta + loads for c+2 ----
        if (c < 7) {
            stage(buf ^ 1);
            mfma_delta(buf ^ 1);
            if (c < 6) { load_chunk((c + 2) * 32); load_afrag(c + 2); }
        }

        // ---- R(c): 32 steps as 4 register-batched groups of 8 ----
        __builtin_amdgcn_s_setprio(1);
        #pragma unroll
        for (int g = 0; g < 4; ++g) {
            floatx4 dxr[4], bcr[8];
            #pragma unroll
            for (int k = 0; k < 4; ++k)
                dxr[k] = *(const floatx4*)&sdx[buf][dslot][(g * 8 + k * 2) * 2];
            #pragma unroll
            for (int k = 0; k < 8; ++k)
                bcr[k] = *(const floatx4*)&sbc[buf][g * 8 + k][np * 4];  // B0,B1,C0,C1
            float yv[8];
            #pragma unroll
            for (int k = 0; k < 8; ++k) {
                float dv = dxr[k >> 1][(k & 1) * 2], xv = dxr[k >> 1][(k & 1) * 2 + 1];
                floatx4 bc = bcr[k];
                floatx2 tt = Av * dv;                          // v_pk_mul_f32
                floatx2 a = { __builtin_amdgcn_exp2f(tt[0]),
                              __builtin_amdgcn_exp2f(tt[1]) };
                float du = dv * xv;
                floatx2 Bp = { bc[0], bc[1] };
                floatx2 Cp = { bc[2], bc[3] };
                h = __builtin_elementwise_fma(a, h, Bp * du);  // pk_mul + pk_fma
                floatx2 qv = h * Cp;                           // v_pk_mul_f32
                float p = qv[0] + qv[1];
                p = grp8_sum(p);
                yv[k] = fmaf(Dpar, xv, p);
            }
            if (np == 0) {
                #pragma unroll
                for (int k = 0; k < 8; ++k)
                    sY[buf][g * 8 + k][dslot] = yv[k];
            }
        }
        __builtin_amdgcn_s_setprio(0);
        __syncthreads();                       // sY[buf] complete; buf^1 staged

        // ---- W(c): ungated write to out-domain (4 floats/thread, 128B rows) ----
        {
            int lout = perm_idx(dir, c * 32 + srow);
            floatx4 o = *(const floatx4*)&sY[buf][srow][sc4];
            *(floatx4*)&ydir[(dirrow + (size_t)b * 256 + lout) * DI + d0 + sc4] = o;
        }
    }
}

// sum of 4 direction outputs, gate by silu(z) -> hi/lo fp16 for out_proj
__global__ __launch_bounds__(256) void k_sum(const float* __restrict__ ydir,
                                             const float* __restrict__ xz,
                                             _Float16* __restrict__ yh,
                                             _Float16* __restrict__ yl) {
    int i4 = (blockIdx.x * 256 + threadIdx.x) * 4;
    const size_t S = (size_t)MROWS * DI;
    int row = i4 / DI, dcol = i4 - row * DI;
    size_t zo = (size_t)row * F2D + DI + dcol;
    floatx4 zv = *(const floatx4*)(xz + zo);
    floatx4 s = *(const floatx4*)(ydir + i4) + *(const floatx4*)(ydir + S + i4) +
                *(const floatx4*)(ydir + 2 * S + i4) + *(const floatx4*)(ydir + 3 * S + i4);
    halfx4 hh, hl;
    #pragma unroll
    for (int e = 0; e < 4; ++e) {
        float g = zv[e] / (1.f + __expf(-zv[e]));
        float v = s[e] * g;
        _Float16 h = (_Float16)v;
        hh[e] = h; hl[e] = (_Float16)(v - (float)h);
    }
    *(halfx4*)(yh + i4) = hh;
    *(halfx4*)(yl + i4) = hl;
}

// ---------------------------------------------------------------------------
extern "C" void kernel_launch(void* const* d_in, const int* in_sizes, int n_in,
                              void* d_out, int out_size, void* d_ws, size_t ws_size,
                              hipStream_t stream) {
    const float* hs   = (const float*)d_in[0];
    const float* wip  = (const float*)d_in[1];
    const float* wop  = (const float*)d_in[2];
    const float* cw   = (const float*)d_in[3];
    const float* cb   = (const float*)d_in[4];
    const float* xw   = (const float*)d_in[5];
    const float* dtw  = (const float*)d_in[6];
    const float* dtb  = (const float*)d_in[7];
    const float* alog = (const float*)d_in[8];
    const float* dpar = (const float*)d_in[9];
    float* out = (float*)d_out;

    char* p = (char*)d_ws;
    auto alloc_f32 = [&](size_t n) { float* r = (float*)p; p += n * 4; return r; };
    auto alloc_f16 = [&](size_t n) { _Float16* r = (_Float16*)p; p += n * 2; return r; };

    _Float16* hsh  = alloc_f16(786432);
    _Float16* hsl  = alloc_f16(786432);
    _Float16* wiph = alloc_f16(2359296);
    _Float16* wipl = alloc_f16(2359296);
    _Float16* woph = alloc_f16(1179648);
    _Float16* wopl = alloc_f16(1179648);
    _Float16* xwh  = alloc_f16(491520);
    _Float16* xwl  = alloc_f16(491520);
    _Float16* dtwh = alloc_f16((size_t)NDIRS * DI * 64);
    _Float16* dtwl = alloc_f16((size_t)NDIRS * DI * 64);
    float*    xz   = alloc_f32((size_t)MROWS * F2D);       // single plane
    _Float16* xh   = alloc_f16((size_t)NDIRS * MROWS * DI);
    _Float16* xl   = alloc_f16((size_t)NDIRS * MROWS * DI);
    _Float16* dtqh = alloc_f16((size_t)NDIRS * MROWS * 64);
    _Float16* dtql = alloc_f16((size_t)NDIRS * MROWS * 64);
    float*    BCm  = alloc_f32((size_t)NDIRS * MROWS * 32);
    float*    oacc = alloc_f32((size_t)4 * MROWS * EI);    // outproj 4 planes
    float*    ydir = alloc_f32((size_t)NDIRS * MROWS * DI);
    _Float16* yh   = alloc_f16((size_t)MROWS * DI);
    _Float16* yl   = alloc_f16((size_t)MROWS * DI);

    // alias onto dead region (disjoint lifetimes):
    float* xdba = ydir;    // xdbl 8 planes (10.5 MB <= 25.2 MB); dead after k_xsplit

    k_splitall<<<dim3(5088), 256, 0, stream>>>(hs, wip, wop, xw, dtw,
                                               hsh, hsl, wiph, wipl, woph, wopl,
                                               xwh, xwl, dtwh, dtwl);
    k_inproj_t<<<dim3(16, 24), 256, 0, stream>>>(hsh, hsl, wiph, wipl, xz);
    k_conv4   <<<dim3(96, BI), 512, 0, stream>>>(xz, cw, cb, xh, xl);
    k_xdbl_t  <<<dim3(16, NDIRS, 8), 256, 0, stream>>>(xh, xl, xwh, xwl, xdba);
    k_xsplit  <<<dim3(1536), 256, 0, stream>>>(xdba, dtqh, dtql, BCm);
    k_scan    <<<dim3(DI / 32, BI, NDIRS), 256, 0, stream>>>(dtqh, dtql, dtwh, dtwl, dtb,
                                                             xh, xl, BCm, alog, dpar, ydir);
    k_sum     <<<dim3(1536), 256, 0, stream>>>(ydir, xz, yh, yl);
    k_outproj_t<<<dim3(16, 6, 4), 256, 0, stream>>>(yh, yl, woph, wopl, oacc);
    k_osum    <<<dim3(768), 256, 0, stream>>>(oacc, out);
}